// Round 6
// baseline (5948.280 us; speedup 1.0000x reference)
//
#include <hip/hip_runtime.h>
#include <math.h>

#define NN 50000
#define NE 800000
#define INF 512
#define HID 64
#define OUTF 40
#define NL 16
#define PADN 65
#define PACCS 17

// ---------------- setup kernels ----------------

__global__ __launch_bounds__(256) void k_deg(const int* __restrict__ src, const int* __restrict__ dst,
                                             int* __restrict__ dout, int* __restrict__ din) {
    int e = blockIdx.x * 256 + threadIdx.x;
    if (e < NE) {
        atomicAdd(&dout[src[e]], 1);
        atomicAdd(&din[dst[e]], 1);
    }
}

__global__ __launch_bounds__(256) void k_norm(const int* __restrict__ dout, const int* __restrict__ din,
                                              float* __restrict__ ns, float* __restrict__ nd) {
    int i = blockIdx.x * 256 + threadIdx.x;
    if (i < NN) {
        ns[i] = 1.0f / sqrtf((float)max(dout[i], 1));
        nd[i] = 1.0f / sqrtf((float)max(din[i], 1));
    }
}

__global__ __launch_bounds__(256) void k_scanA(const int* __restrict__ din, int* __restrict__ incl,
                                               int* __restrict__ bsum) {
    __shared__ int lds[256];
    int i = blockIdx.x * 256 + threadIdx.x;
    int v = (i < NN) ? din[i] : 0;
    lds[threadIdx.x] = v;
    __syncthreads();
    for (int off = 1; off < 256; off <<= 1) {
        int t = (threadIdx.x >= off) ? lds[threadIdx.x - off] : 0;
        __syncthreads();
        lds[threadIdx.x] += t;
        __syncthreads();
    }
    if (i < NN) incl[i] = lds[threadIdx.x];
    if (threadIdx.x == 255) bsum[blockIdx.x] = lds[255];
}

__global__ __launch_bounds__(256) void k_scanB(int* __restrict__ bsum, int nb) {
    __shared__ int lds[256];
    int v = (threadIdx.x < nb) ? bsum[threadIdx.x] : 0;
    lds[threadIdx.x] = v;
    __syncthreads();
    for (int off = 1; off < 256; off <<= 1) {
        int t = (threadIdx.x >= off) ? lds[threadIdx.x - off] : 0;
        __syncthreads();
        lds[threadIdx.x] += t;
        __syncthreads();
    }
    if (threadIdx.x < nb) bsum[threadIdx.x] = lds[threadIdx.x] - v;  // exclusive
}

__global__ __launch_bounds__(256) void k_scanC(const int* __restrict__ incl, const int* __restrict__ din,
                                               const int* __restrict__ bsum, int* __restrict__ row_start,
                                               int* __restrict__ cursor) {
    int i = blockIdx.x * 256 + threadIdx.x;
    if (i < NN) {
        int rs = incl[i] - din[i] + bsum[i >> 8];
        row_start[i] = rs;
        cursor[i] = rs;
    }
}

// CSR fill; also records each slot's dst node (edge-centric agg needs it)
__global__ __launch_bounds__(256) void k_fill(const int* __restrict__ src, const int* __restrict__ dst,
                                              int* __restrict__ cursor, int* __restrict__ col,
                                              int* __restrict__ edst) {
    int e = blockIdx.x * 256 + threadIdx.x;
    if (e < NE) {
        int d = dst[e];
        int p = atomicAdd(&cursor[d], 1);
        col[p] = src[e];
        edst[p] = d;
    }
}

__global__ __launch_bounds__(256) void k_wprep(const float* __restrict__ W1, const float* __restrict__ W2,
                                               float* __restrict__ w1p, float* __restrict__ w2p) {
    int i = blockIdx.x * 256 + threadIdx.x;
    if (i < NL * HID * HID) {
        int l = i >> 12;
        int rc = i & 4095;
        int r = rc >> 6;
        int c = rc & 63;
        float beta = logf(0.5f / (float)(l + 1) + 1.0f);
        float d = (r == c) ? (1.0f - beta) : 0.0f;
        w1p[i] = beta * W1[i] + d;
        w2p[i] = beta * W2[i] + d;
    }
}

// ---------------- h0 GEMM: 512 thr, lane = node, wave = 8-col group (scalar weights, 2-deep pipeline) ----------------
__global__ __launch_bounds__(512) void k_gemm0(const float* __restrict__ feat, const float* __restrict__ Win,
                                               const float* __restrict__ bin, const float* __restrict__ ns,
                                               float* __restrict__ hs, float* __restrict__ f0) {
    int lane = threadIdx.x & 63;
    int cg = __builtin_amdgcn_readfirstlane(threadIdx.x >> 6) * 8;  // 0..56
    int node = blockIdx.x * 64 + lane;
    int nodec = min(node, NN - 1);
    const float4* frow = (const float4*)(feat + (size_t)nodec * INF);
    const float* wbase = Win + cg;
    float acc[8];
#pragma unroll
    for (int c = 0; c < 8; c++) acc[c] = 0.0f;

    float4 r0 = frow[0], r1 = frow[1];
    for (int kk = 0; kk + 2 < INF / 4; kk += 2) {
        float4 n0 = frow[kk + 2], n1 = frow[kk + 3];
        float av[8] = {r0.x, r0.y, r0.z, r0.w, r1.x, r1.y, r1.z, r1.w};
#pragma unroll
        for (int j = 0; j < 8; j++) {
            const float* wr = wbase + (size_t)(kk * 4 + j) * HID;
#pragma unroll
            for (int c = 0; c < 8; c++) acc[c] += av[j] * wr[c];
        }
        r0 = n0; r1 = n1;
    }
    {
        int kk = INF / 4 - 2;
        float av[8] = {r0.x, r0.y, r0.z, r0.w, r1.x, r1.y, r1.z, r1.w};
#pragma unroll
        for (int j = 0; j < 8; j++) {
            const float* wr = wbase + (size_t)(kk * 4 + j) * HID;
#pragma unroll
            for (int c = 0; c < 8; c++) acc[c] += av[j] * wr[c];
        }
    }
    if (node < NN) {
        float nsv = ns[node];
        const float* bp = bin + cg;
        float4* hsp = (float4*)(hs + (size_t)node * HID + cg);
        float4* f0p = (float4*)(f0 + (size_t)node * HID + cg);
#pragma unroll
        for (int c4 = 0; c4 < 2; c4++) {
            float q0 = fmaxf(acc[c4 * 4 + 0] + bp[c4 * 4 + 0], 0.0f);
            float q1 = fmaxf(acc[c4 * 4 + 1] + bp[c4 * 4 + 1], 0.0f);
            float q2 = fmaxf(acc[c4 * 4 + 2] + bp[c4 * 4 + 2], 0.0f);
            float q3 = fmaxf(acc[c4 * 4 + 3] + bp[c4 * 4 + 3], 0.0f);
            float4 vs = {q0 * nsv, q1 * nsv, q2 * nsv, q3 * nsv};
            hsp[c4] = vs;
            float4 vf = {q0 * 0.1f, q1 * 0.1f, q2 * 0.1f, q3 * 0.1f};
            f0p[c4] = vf;
        }
    }
}

// ---------------- fused layer: edge-centric agg (LDS atomics) + split matmul ----------------
// 512 threads. Block owns dst-nodes [nb, nb+64); their CSR edges are contiguous.
__global__ __launch_bounds__(512) void k_layer(const float* __restrict__ hs_in, const int* __restrict__ col,
                                               const int* __restrict__ edst, const int* __restrict__ row_start,
                                               const float* __restrict__ nd, const float* __restrict__ f0,
                                               const float* __restrict__ w1p, const float* __restrict__ w2p,
                                               const float* __restrict__ bias, const float* __restrict__ ns,
                                               float* __restrict__ h, float* __restrict__ hs_out, int write_h) {
    __shared__ float fT[HID * PADN];
    __shared__ float f0T[HID * PADN];
    __shared__ float pacc[4 * 64 * PACCS];
    int tid = threadIdx.x;
    int lane = tid & 63;
    int wv = tid >> 6;  // 0..7
    int nb = blockIdx.x * 64;

    // zero accumulation tile
    for (int i = tid; i < HID * PADN; i += 512) fT[i] = 0.0f;
    // stage f0 rows -> LDS transposed (coalesced 16B reads)
    for (int i = tid; i < 64 * 16; i += 512) {
        int nl = i >> 4;
        int c4 = i & 15;
        int n = min(nb + nl, NN - 1);
        float4 v = *(const float4*)(f0 + (size_t)n * HID + c4 * 4);
        f0T[(c4 * 4 + 0) * PADN + nl] = v.x;
        f0T[(c4 * 4 + 1) * PADN + nl] = v.y;
        f0T[(c4 * 4 + 2) * PADN + nl] = v.z;
        f0T[(c4 * 4 + 3) * PADN + nl] = v.w;
    }
    __syncthreads();

    // edge-centric aggregation: 16-lane group = one edge (full 64-dim row); 32 edges in flight per block
    int ebeg = row_start[nb];
    int eend = (nb + 64 < NN) ? row_start[nb + 64] : NE;
    int egrp = lane >> 4;
    int c4o = (lane & 15) << 2;
    for (int e0 = ebeg + wv * 4; e0 < eend; e0 += 32) {
        int e = e0 + egrp;
        if (e < eend) {
            int s = col[e];
            int d = edst[e] - nb;
            float4 v = *(const float4*)(hs_in + (size_t)s * HID + c4o);
            atomicAdd(&fT[(c4o + 0) * PADN + d], v.x);
            atomicAdd(&fT[(c4o + 1) * PADN + d], v.y);
            atomicAdd(&fT[(c4o + 2) * PADN + d], v.z);
            atomicAdd(&fT[(c4o + 3) * PADN + d], v.w);
        }
    }
    __syncthreads();

    // scale: fT[k][nl] *= 0.9 * nd
    for (int i = tid; i < HID * 64; i += 512) {
        int dim = i >> 6;
        int nl = i & 63;
        int n = nb + nl;
        float sc = (n < NN) ? 0.9f * nd[n] : 0.0f;
        fT[dim * PADN + nl] *= sc;
    }
    __syncthreads();

    // matmul: lane = node. waves 0-3: f @ w1p (cg = wv*16); waves 4-7: f0 @ w2p (cg = (wv-4)*16)
    int cgl = wv & 3;
    int cg = __builtin_amdgcn_readfirstlane(cgl) * 16;
    float acc[16];
#pragma unroll
    for (int c = 0; c < 16; c++) acc[c] = 0.0f;
    if (wv >= 4) {
        const float* w2b = w2p + cg;
        for (int k = 0; k < HID; ++k) {
            float f0k = f0T[k * PADN + lane];
            const float* w2r = w2b + (size_t)k * HID;
#pragma unroll
            for (int c = 0; c < 16; c++) acc[c] += f0k * w2r[c];
        }
        float* pp = pacc + ((size_t)cgl * 64 + lane) * PACCS;
#pragma unroll
        for (int c = 0; c < 16; c++) pp[c] = acc[c];
    } else {
        const float* w1b = w1p + cg;
        for (int k = 0; k < HID; ++k) {
            float fk = fT[k * PADN + lane];
            const float* w1r = w1b + (size_t)k * HID;
#pragma unroll
            for (int c = 0; c < 16; c++) acc[c] += fk * w1r[c];
        }
    }
    __syncthreads();
    if (wv < 4) {
        const float* pp = pacc + ((size_t)cgl * 64 + lane) * PACCS;
        int node = nb + lane;
        if (node < NN) {
            float nsv = ns[node];
            const float* bp = bias + cg;
            float4* hsp = (float4*)(hs_out + (size_t)node * HID + cg);
#pragma unroll
            for (int c4 = 0; c4 < 4; c4++) {
                float q0 = fmaxf(acc[c4 * 4 + 0] + pp[c4 * 4 + 0] + bp[c4 * 4 + 0], 0.0f);
                float q1 = fmaxf(acc[c4 * 4 + 1] + pp[c4 * 4 + 1] + bp[c4 * 4 + 1], 0.0f);
                float q2 = fmaxf(acc[c4 * 4 + 2] + pp[c4 * 4 + 2] + bp[c4 * 4 + 2], 0.0f);
                float q3 = fmaxf(acc[c4 * 4 + 3] + pp[c4 * 4 + 3] + bp[c4 * 4 + 3], 0.0f);
                float4 vs = {q0 * nsv, q1 * nsv, q2 * nsv, q3 * nsv};
                hsp[c4] = vs;
                if (write_h) {
                    float4 v = {q0, q1, q2, q3};
                    ((float4*)(h + (size_t)node * HID + cg))[c4] = v;
                }
            }
        }
    }
}

// ---------------- output: block = 128 nodes; wave pair splits the 40 cols; LDS lse reduce ----------------
__global__ __launch_bounds__(256) void k_out(const float* __restrict__ h, const float* __restrict__ Wout,
                                             const float* __restrict__ bout, float* __restrict__ out) {
    __shared__ float red_mx[4][64];
    __shared__ float red_s[4][64];
    int tid = threadIdx.x;
    int lane = tid & 63;
    int wv = tid >> 6;
    int half = wv & 1;
    int grp = wv >> 1;
    int node = blockIdx.x * 128 + grp * 64 + lane;
    int nodec = min(node, NN - 1);
    float acc[20];
#pragma unroll
    for (int c = 0; c < 20; c++) acc[c] = 0.0f;
    const float4* hr = (const float4*)(h + (size_t)nodec * HID);
    const float* wb = Wout + half * 20;
    for (int kk = 0; kk < HID / 4; ++kk) {
        float4 a = hr[kk];
        float av[4] = {a.x, a.y, a.z, a.w};
#pragma unroll
        for (int j = 0; j < 4; j++) {
            const float* wr = wb + (size_t)(kk * 4 + j) * OUTF;
#pragma unroll
            for (int c = 0; c < 20; c++) acc[c] += av[j] * wr[c];
        }
    }
    const float* bp = bout + half * 20;
#pragma unroll
    for (int c = 0; c < 20; c++) acc[c] += bp[c];
    float mx = acc[0];
#pragma unroll
    for (int c = 1; c < 20; c++) mx = fmaxf(mx, acc[c]);
    red_mx[wv][lane] = mx;
    __syncthreads();
    float gmx = fmaxf(mx, red_mx[wv ^ 1][lane]);
    float s = 0.0f;
#pragma unroll
    for (int c = 0; c < 20; c++) s += expf(acc[c] - gmx);
    red_s[wv][lane] = s;
    __syncthreads();
    float lse = logf(s + red_s[wv ^ 1][lane]) + gmx;
    if (node < NN) {
        float4* op = (float4*)(out + (size_t)node * OUTF + half * 20);
#pragma unroll
        for (int q = 0; q < 5; q++) {
            float4 v;
            v.x = acc[q * 4 + 0] - lse;
            v.y = acc[q * 4 + 1] - lse;
            v.z = acc[q * 4 + 2] - lse;
            v.w = acc[q * 4 + 3] - lse;
            op[q] = v;
        }
    }
}

extern "C" void kernel_launch(void* const* d_in, const int* in_sizes, int n_in,
                              void* d_out, int out_size, void* d_ws, size_t ws_size,
                              hipStream_t stream) {
    const float* feat = (const float*)d_in[0];
    const float* Win  = (const float*)d_in[1];
    const float* bin  = (const float*)d_in[2];
    const float* W1   = (const float*)d_in[3];
    const float* W2   = (const float*)d_in[4];
    const float* bvec = (const float*)d_in[5];
    const float* Wout = (const float*)d_in[6];
    const float* bout = (const float*)d_in[7];
    const int*   src  = (const int*)d_in[8];
    const int*   dst  = (const int*)d_in[9];
    float* out = (float*)d_out;

    char* ws = (char*)d_ws;
    size_t off = 0;
    auto take = [&](size_t bytes) {
        void* p = ws + off;
        off += (bytes + 255) & ~(size_t)255;
        return p;
    };
    int* deg_out   = (int*)take(NN * 4);
    int* deg_in    = (int*)take(NN * 4);
    int* incl      = (int*)take(NN * 4);
    int* bsum      = (int*)take(256 * 4);
    int* row_start = (int*)take(NN * 4);
    int* cursor    = (int*)take(NN * 4);
    int* col       = (int*)take(NE * 4);
    int* edst      = (int*)take(NE * 4);
    float* nsrc    = (float*)take(NN * 4);
    float* ndst    = (float*)take(NN * 4);
    float* w1p     = (float*)take((size_t)NL * HID * HID * 4);
    float* w2p     = (float*)take((size_t)NL * HID * HID * 4);
    float* f0      = (float*)take((size_t)NN * HID * 4);
    float* hbuf    = (float*)take((size_t)NN * HID * 4);
    float* hsA     = (float*)take((size_t)NN * HID * 4);
    float* hsB     = (float*)take((size_t)NN * HID * 4);

    const int NB_N = (NN + 255) / 256;   // 196
    const int NB_E = (NE + 255) / 256;   // 3125
    const int NB_W = (NN + 63) / 64;     // 782
    const int NB_O = (NN + 127) / 128;   // 391

    hipMemsetAsync(deg_out, 0, NN * 4, stream);
    hipMemsetAsync(deg_in, 0, NN * 4, stream);

    k_deg<<<NB_E, 256, 0, stream>>>(src, dst, deg_out, deg_in);
    k_norm<<<NB_N, 256, 0, stream>>>(deg_out, deg_in, nsrc, ndst);
    k_scanA<<<NB_N, 256, 0, stream>>>(deg_in, incl, bsum);
    k_scanB<<<1, 256, 0, stream>>>(bsum, NB_N);
    k_scanC<<<NB_N, 256, 0, stream>>>(incl, deg_in, bsum, row_start, cursor);
    k_fill<<<NB_E, 256, 0, stream>>>(src, dst, cursor, col, edst);
    k_wprep<<<(NL * HID * HID + 255) / 256, 256, 0, stream>>>(W1, W2, w1p, w2p);
    k_gemm0<<<NB_W, 512, 0, stream>>>(feat, Win, bin, nsrc, hsA, f0);

    // ping-pong hs buffers (gathers read arbitrary rows; in-place would race)
    for (int l = 0; l < NL; ++l) {
        const float* hin = (l & 1) ? hsB : hsA;
        float* hout = (l & 1) ? hsA : hsB;
        k_layer<<<NB_W, 512, 0, stream>>>(hin, col, edst, row_start, ndst, f0,
                                          w1p + l * HID * HID, w2p + l * HID * HID,
                                          bvec + l * HID, nsrc, hbuf, hout, (l == NL - 1) ? 1 : 0);
    }
    k_out<<<NB_O, 256, 0, stream>>>(hbuf, Wout, bout, out);
}

// Round 7
// 1366.200 us; speedup vs baseline: 4.3539x; 4.3539x over previous
//
#include <hip/hip_runtime.h>
#include <math.h>

#define NN 50000
#define NE 800000
#define INF 512
#define HID 64
#define OUTF 40
#define NL 16
#define PADN 65
#define PACCS 17

// ---------------- setup kernels ----------------

__global__ __launch_bounds__(256) void k_deg(const int* __restrict__ src, const int* __restrict__ dst,
                                             int* __restrict__ dout, int* __restrict__ din) {
    int e = blockIdx.x * 256 + threadIdx.x;
    if (e < NE) {
        atomicAdd(&dout[src[e]], 1);
        atomicAdd(&din[dst[e]], 1);
    }
}

__global__ __launch_bounds__(256) void k_norm(const int* __restrict__ dout, const int* __restrict__ din,
                                              float* __restrict__ ns, float* __restrict__ nd) {
    int i = blockIdx.x * 256 + threadIdx.x;
    if (i < NN) {
        ns[i] = 1.0f / sqrtf((float)max(dout[i], 1));
        nd[i] = 1.0f / sqrtf((float)max(din[i], 1));
    }
}

__global__ __launch_bounds__(256) void k_scanA(const int* __restrict__ din, int* __restrict__ incl,
                                               int* __restrict__ bsum) {
    __shared__ int lds[256];
    int i = blockIdx.x * 256 + threadIdx.x;
    int v = (i < NN) ? din[i] : 0;
    lds[threadIdx.x] = v;
    __syncthreads();
    for (int off = 1; off < 256; off <<= 1) {
        int t = (threadIdx.x >= off) ? lds[threadIdx.x - off] : 0;
        __syncthreads();
        lds[threadIdx.x] += t;
        __syncthreads();
    }
    if (i < NN) incl[i] = lds[threadIdx.x];
    if (threadIdx.x == 255) bsum[blockIdx.x] = lds[255];
}

__global__ __launch_bounds__(256) void k_scanB(int* __restrict__ bsum, int nb) {
    __shared__ int lds[256];
    int v = (threadIdx.x < nb) ? bsum[threadIdx.x] : 0;
    lds[threadIdx.x] = v;
    __syncthreads();
    for (int off = 1; off < 256; off <<= 1) {
        int t = (threadIdx.x >= off) ? lds[threadIdx.x - off] : 0;
        __syncthreads();
        lds[threadIdx.x] += t;
        __syncthreads();
    }
    if (threadIdx.x < nb) bsum[threadIdx.x] = lds[threadIdx.x] - v;  // exclusive
}

__global__ __launch_bounds__(256) void k_scanC(const int* __restrict__ incl, const int* __restrict__ din,
                                               const int* __restrict__ bsum, int* __restrict__ row_start,
                                               int* __restrict__ cursor) {
    int i = blockIdx.x * 256 + threadIdx.x;
    if (i < NN) {
        int rs = incl[i] - din[i] + bsum[i >> 8];
        row_start[i] = rs;
        cursor[i] = rs;
    }
}

__global__ __launch_bounds__(256) void k_fill(const int* __restrict__ src, const int* __restrict__ dst,
                                              int* __restrict__ cursor, int* __restrict__ col) {
    int e = blockIdx.x * 256 + threadIdx.x;
    if (e < NE) {
        int d = dst[e];
        int p = atomicAdd(&cursor[d], 1);
        col[p] = src[e];
    }
}

__global__ __launch_bounds__(256) void k_wprep(const float* __restrict__ W1, const float* __restrict__ W2,
                                               float* __restrict__ w1p, float* __restrict__ w2p) {
    int i = blockIdx.x * 256 + threadIdx.x;
    if (i < NL * HID * HID) {
        int l = i >> 12;
        int rc = i & 4095;
        int r = rc >> 6;
        int c = rc & 63;
        float beta = logf(0.5f / (float)(l + 1) + 1.0f);
        float d = (r == c) ? (1.0f - beta) : 0.0f;
        w1p[i] = beta * W1[i] + d;
        w2p[i] = beta * W2[i] + d;
    }
}

// ---------------- h0 GEMM: 512 thr, lane = node, wave = 8-col group (scalar weights, 2-deep pipeline) ----------------
__global__ __launch_bounds__(512) void k_gemm0(const float* __restrict__ feat, const float* __restrict__ Win,
                                               const float* __restrict__ bin, const float* __restrict__ ns,
                                               float* __restrict__ hs, float* __restrict__ f0) {
    int lane = threadIdx.x & 63;
    int cg = __builtin_amdgcn_readfirstlane(threadIdx.x >> 6) * 8;  // 0..56
    int node = blockIdx.x * 64 + lane;
    int nodec = min(node, NN - 1);
    const float4* frow = (const float4*)(feat + (size_t)nodec * INF);
    const float* wbase = Win + cg;
    float acc[8];
#pragma unroll
    for (int c = 0; c < 8; c++) acc[c] = 0.0f;

    float4 r0 = frow[0], r1 = frow[1];
    for (int kk = 0; kk + 2 < INF / 4; kk += 2) {
        float4 n0 = frow[kk + 2], n1 = frow[kk + 3];
        float av[8] = {r0.x, r0.y, r0.z, r0.w, r1.x, r1.y, r1.z, r1.w};
#pragma unroll
        for (int j = 0; j < 8; j++) {
            const float* wr = wbase + (size_t)(kk * 4 + j) * HID;
#pragma unroll
            for (int c = 0; c < 8; c++) acc[c] += av[j] * wr[c];
        }
        r0 = n0; r1 = n1;
    }
    {
        int kk = INF / 4 - 2;
        float av[8] = {r0.x, r0.y, r0.z, r0.w, r1.x, r1.y, r1.z, r1.w};
#pragma unroll
        for (int j = 0; j < 8; j++) {
            const float* wr = wbase + (size_t)(kk * 4 + j) * HID;
#pragma unroll
            for (int c = 0; c < 8; c++) acc[c] += av[j] * wr[c];
        }
    }
    if (node < NN) {
        float nsv = ns[node];
        const float* bp = bin + cg;
        float4* hsp = (float4*)(hs + (size_t)node * HID + cg);
        float4* f0p = (float4*)(f0 + (size_t)node * HID + cg);
#pragma unroll
        for (int c4 = 0; c4 < 2; c4++) {
            float q0 = fmaxf(acc[c4 * 4 + 0] + bp[c4 * 4 + 0], 0.0f);
            float q1 = fmaxf(acc[c4 * 4 + 1] + bp[c4 * 4 + 1], 0.0f);
            float q2 = fmaxf(acc[c4 * 4 + 2] + bp[c4 * 4 + 2], 0.0f);
            float q3 = fmaxf(acc[c4 * 4 + 3] + bp[c4 * 4 + 3], 0.0f);
            float4 vs = {q0 * nsv, q1 * nsv, q2 * nsv, q3 * nsv};
            hsp[c4] = vs;
            float4 vf = {q0 * 0.1f, q1 * 0.1f, q2 * 0.1f, q3 * 0.1f};
            f0p[c4] = vf;
        }
    }
}

// ---------------- fused layer: 8 waves. agg = R5 gather structure (8 nodes/wave); split matmul ----------------
__global__ __launch_bounds__(512) void k_layer(const float* __restrict__ hs_in, const int* __restrict__ col,
                                               const int* __restrict__ row_start, const int* __restrict__ din,
                                               const float* __restrict__ nd, const float* __restrict__ f0,
                                               const float* __restrict__ w1p, const float* __restrict__ w2p,
                                               const float* __restrict__ bias, const float* __restrict__ ns,
                                               float* __restrict__ h, float* __restrict__ hs_out, int write_h) {
    __shared__ float fT[HID * PADN];
    __shared__ float f0T[HID * PADN];
    __shared__ float pacc[4 * 64 * PACCS];
    int tid = threadIdx.x;
    int lane = tid & 63;
    int wv = tid >> 6;  // 0..7
    int nb = blockIdx.x * 64;
    int grp = lane >> 4;         // edge slot within a 4-edge round
    int c4o = (lane & 15) << 2;  // feature dims [c4o, c4o+4)

    // stage f0 rows -> LDS transposed (coalesced 16B global reads)
    for (int i = tid; i < 64 * 16; i += 512) {
        int nl = i >> 4;
        int c4 = i & 15;
        int n = min(nb + nl, NN - 1);
        float4 v = *(const float4*)(f0 + (size_t)n * HID + c4 * 4);
        f0T[(c4 * 4 + 0) * PADN + nl] = v.x;
        f0T[(c4 * 4 + 1) * PADN + nl] = v.y;
        f0T[(c4 * 4 + 2) * PADN + nl] = v.z;
        f0T[(c4 * 4 + 3) * PADN + nl] = v.w;
    }

    // aggregation: wave wv handles 8 nodes serially; 16 edges (4 float4 gathers/lane) in flight per round
    int n0 = min(nb + wv * 8, NN - 1);
    int base_cur = row_start[n0];
    int deg_cur = din[n0];
    int idx_cur = (lane < min(deg_cur, 64)) ? col[base_cur + lane] : 0;

    for (int i = 0; i < 8; ++i) {
        int nl = wv * 8 + i;
        int n = min(nb + nl, NN - 1);
        // prefetch next node's first edge batch
        int base_nx = 0, deg_nx = 0, idx_nx = 0;
        if (i < 7) {
            int n2 = min(nb + nl + 1, NN - 1);
            base_nx = row_start[n2];
            deg_nx = din[n2];
            idx_nx = (lane < min(deg_nx, 64)) ? col[base_nx + lane] : 0;
        }
        float ax = 0.0f, ay = 0.0f, az = 0.0f, aw = 0.0f;
        int deg = deg_cur, base = base_cur, idxv = idx_cur;
        for (int done = 0; done < deg;) {
            int cnt = min(64, deg - done);
            if (done) idxv = (lane < cnt) ? col[base + done + lane] : 0;
            int e = 0;
            for (; e + 16 <= cnt; e += 16) {
                int s0 = __shfl(idxv, e + grp, 64);
                int s1 = __shfl(idxv, e + 4 + grp, 64);
                int s2 = __shfl(idxv, e + 8 + grp, 64);
                int s3 = __shfl(idxv, e + 12 + grp, 64);
                float4 v0 = *(const float4*)(hs_in + (size_t)s0 * HID + c4o);
                float4 v1 = *(const float4*)(hs_in + (size_t)s1 * HID + c4o);
                float4 v2 = *(const float4*)(hs_in + (size_t)s2 * HID + c4o);
                float4 v3 = *(const float4*)(hs_in + (size_t)s3 * HID + c4o);
                ax += (v0.x + v1.x) + (v2.x + v3.x);
                ay += (v0.y + v1.y) + (v2.y + v3.y);
                az += (v0.z + v1.z) + (v2.z + v3.z);
                aw += (v0.w + v1.w) + (v2.w + v3.w);
            }
            if (e + 8 <= cnt) {
                int s0 = __shfl(idxv, e + grp, 64);
                int s1 = __shfl(idxv, e + 4 + grp, 64);
                float4 v0 = *(const float4*)(hs_in + (size_t)s0 * HID + c4o);
                float4 v1 = *(const float4*)(hs_in + (size_t)s1 * HID + c4o);
                ax += v0.x + v1.x;
                ay += v0.y + v1.y;
                az += v0.z + v1.z;
                aw += v0.w + v1.w;
                e += 8;
            }
            if (e < cnt) {
                int ei0 = e + grp;
                int ei1 = e + 4 + grp;
                int s0 = __shfl(idxv, ei0 & 63, 64);
                int s1 = __shfl(idxv, ei1 & 63, 64);
                if (ei0 < cnt) {
                    float4 v0 = *(const float4*)(hs_in + (size_t)s0 * HID + c4o);
                    ax += v0.x; ay += v0.y; az += v0.z; aw += v0.w;
                }
                if (ei1 < cnt) {
                    float4 v1 = *(const float4*)(hs_in + (size_t)s1 * HID + c4o);
                    ax += v1.x; ay += v1.y; az += v1.z; aw += v1.w;
                }
            }
            done += cnt;
        }
        ax += __shfl_xor(ax, 16, 64); ax += __shfl_xor(ax, 32, 64);
        ay += __shfl_xor(ay, 16, 64); ay += __shfl_xor(ay, 32, 64);
        az += __shfl_xor(az, 16, 64); az += __shfl_xor(az, 32, 64);
        aw += __shfl_xor(aw, 16, 64); aw += __shfl_xor(aw, 32, 64);
        float sc = 0.9f * nd[n];
        if (grp == 0) {  // lanes 0..15 write 4 dims each, transposed
            fT[(c4o + 0) * PADN + nl] = ax * sc;
            fT[(c4o + 1) * PADN + nl] = ay * sc;
            fT[(c4o + 2) * PADN + nl] = az * sc;
            fT[(c4o + 3) * PADN + nl] = aw * sc;
        }
        base_cur = base_nx; deg_cur = deg_nx; idx_cur = idx_nx;
    }
    __syncthreads();

    // matmul: lane = node. waves 0-3: f @ w1p; waves 4-7: f0 @ w2p (cg = (wv&3)*16); scalar weights
    int cgl = wv & 3;
    int cg = __builtin_amdgcn_readfirstlane(cgl) * 16;
    float acc[16];
#pragma unroll
    for (int c = 0; c < 16; c++) acc[c] = 0.0f;
    if (wv >= 4) {
        const float* w2b = w2p + cg;
        for (int k = 0; k < HID; ++k) {
            float f0k = f0T[k * PADN + lane];
            const float* w2r = w2b + (size_t)k * HID;
#pragma unroll
            for (int c = 0; c < 16; c++) acc[c] += f0k * w2r[c];
        }
        float* pp = pacc + ((size_t)cgl * 64 + lane) * PACCS;
#pragma unroll
        for (int c = 0; c < 16; c++) pp[c] = acc[c];
    } else {
        const float* w1b = w1p + cg;
        for (int k = 0; k < HID; ++k) {
            float fk = fT[k * PADN + lane];
            const float* w1r = w1b + (size_t)k * HID;
#pragma unroll
            for (int c = 0; c < 16; c++) acc[c] += fk * w1r[c];
        }
    }
    __syncthreads();
    if (wv < 4) {
        const float* pp = pacc + ((size_t)cgl * 64 + lane) * PACCS;
        int node = nb + lane;
        if (node < NN) {
            float nsv = ns[node];
            const float* bp = bias + cg;
            float4* hsp = (float4*)(hs_out + (size_t)node * HID + cg);
#pragma unroll
            for (int c4 = 0; c4 < 4; c4++) {
                float q0 = fmaxf(acc[c4 * 4 + 0] + pp[c4 * 4 + 0] + bp[c4 * 4 + 0], 0.0f);
                float q1 = fmaxf(acc[c4 * 4 + 1] + pp[c4 * 4 + 1] + bp[c4 * 4 + 1], 0.0f);
                float q2 = fmaxf(acc[c4 * 4 + 2] + pp[c4 * 4 + 2] + bp[c4 * 4 + 2], 0.0f);
                float q3 = fmaxf(acc[c4 * 4 + 3] + pp[c4 * 4 + 3] + bp[c4 * 4 + 3], 0.0f);
                float4 vs = {q0 * nsv, q1 * nsv, q2 * nsv, q3 * nsv};
                hsp[c4] = vs;
                if (write_h) {
                    float4 v = {q0, q1, q2, q3};
                    ((float4*)(h + (size_t)node * HID + cg))[c4] = v;
                }
            }
        }
    }
}

// ---------------- output: block = 128 nodes; wave pair splits the 40 cols; LDS lse reduce ----------------
__global__ __launch_bounds__(256) void k_out(const float* __restrict__ h, const float* __restrict__ Wout,
                                             const float* __restrict__ bout, float* __restrict__ out) {
    __shared__ float red_mx[4][64];
    __shared__ float red_s[4][64];
    int tid = threadIdx.x;
    int lane = tid & 63;
    int wv = tid >> 6;
    int half = wv & 1;
    int grp = wv >> 1;
    int node = blockIdx.x * 128 + grp * 64 + lane;
    int nodec = min(node, NN - 1);
    float acc[20];
#pragma unroll
    for (int c = 0; c < 20; c++) acc[c] = 0.0f;
    const float4* hr = (const float4*)(h + (size_t)nodec * HID);
    const float* wb = Wout + half * 20;
    for (int kk = 0; kk < HID / 4; ++kk) {
        float4 a = hr[kk];
        float av[4] = {a.x, a.y, a.z, a.w};
#pragma unroll
        for (int j = 0; j < 4; j++) {
            const float* wr = wb + (size_t)(kk * 4 + j) * OUTF;
#pragma unroll
            for (int c = 0; c < 20; c++) acc[c] += av[j] * wr[c];
        }
    }
    const float* bp = bout + half * 20;
#pragma unroll
    for (int c = 0; c < 20; c++) acc[c] += bp[c];
    float mx = acc[0];
#pragma unroll
    for (int c = 1; c < 20; c++) mx = fmaxf(mx, acc[c]);
    red_mx[wv][lane] = mx;
    __syncthreads();
    float gmx = fmaxf(mx, red_mx[wv ^ 1][lane]);
    float s = 0.0f;
#pragma unroll
    for (int c = 0; c < 20; c++) s += expf(acc[c] - gmx);
    red_s[wv][lane] = s;
    __syncthreads();
    float lse = logf(s + red_s[wv ^ 1][lane]) + gmx;
    if (node < NN) {
        float4* op = (float4*)(out + (size_t)node * OUTF + half * 20);
#pragma unroll
        for (int q = 0; q < 5; q++) {
            float4 v;
            v.x = acc[q * 4 + 0] - lse;
            v.y = acc[q * 4 + 1] - lse;
            v.z = acc[q * 4 + 2] - lse;
            v.w = acc[q * 4 + 3] - lse;
            op[q] = v;
        }
    }
}

extern "C" void kernel_launch(void* const* d_in, const int* in_sizes, int n_in,
                              void* d_out, int out_size, void* d_ws, size_t ws_size,
                              hipStream_t stream) {
    const float* feat = (const float*)d_in[0];
    const float* Win  = (const float*)d_in[1];
    const float* bin  = (const float*)d_in[2];
    const float* W1   = (const float*)d_in[3];
    const float* W2   = (const float*)d_in[4];
    const float* bvec = (const float*)d_in[5];
    const float* Wout = (const float*)d_in[6];
    const float* bout = (const float*)d_in[7];
    const int*   src  = (const int*)d_in[8];
    const int*   dst  = (const int*)d_in[9];
    float* out = (float*)d_out;

    char* ws = (char*)d_ws;
    size_t off = 0;
    auto take = [&](size_t bytes) {
        void* p = ws + off;
        off += (bytes + 255) & ~(size_t)255;
        return p;
    };
    int* deg_out   = (int*)take(NN * 4);
    int* deg_in    = (int*)take(NN * 4);
    int* incl      = (int*)take(NN * 4);
    int* bsum      = (int*)take(256 * 4);
    int* row_start = (int*)take(NN * 4);
    int* cursor    = (int*)take(NN * 4);
    int* col       = (int*)take(NE * 4);
    float* nsrc    = (float*)take(NN * 4);
    float* ndst    = (float*)take(NN * 4);
    float* w1p     = (float*)take((size_t)NL * HID * HID * 4);
    float* w2p     = (float*)take((size_t)NL * HID * HID * 4);
    float* f0      = (float*)take((size_t)NN * HID * 4);
    float* hbuf    = (float*)take((size_t)NN * HID * 4);
    float* hsA     = (float*)take((size_t)NN * HID * 4);
    float* hsB     = (float*)take((size_t)NN * HID * 4);

    const int NB_N = (NN + 255) / 256;   // 196
    const int NB_E = (NE + 255) / 256;   // 3125
    const int NB_W = (NN + 63) / 64;     // 782
    const int NB_O = (NN + 127) / 128;   // 391

    hipMemsetAsync(deg_out, 0, NN * 4, stream);
    hipMemsetAsync(deg_in, 0, NN * 4, stream);

    k_deg<<<NB_E, 256, 0, stream>>>(src, dst, deg_out, deg_in);
    k_norm<<<NB_N, 256, 0, stream>>>(deg_out, deg_in, nsrc, ndst);
    k_scanA<<<NB_N, 256, 0, stream>>>(deg_in, incl, bsum);
    k_scanB<<<1, 256, 0, stream>>>(bsum, NB_N);
    k_scanC<<<NB_N, 256, 0, stream>>>(incl, deg_in, bsum, row_start, cursor);
    k_fill<<<NB_E, 256, 0, stream>>>(src, dst, cursor, col);
    k_wprep<<<(NL * HID * HID + 255) / 256, 256, 0, stream>>>(W1, W2, w1p, w2p);
    k_gemm0<<<NB_W, 512, 0, stream>>>(feat, Win, bin, nsrc, hsA, f0);

    // ping-pong hs buffers (gathers read arbitrary rows; in-place would race)
    for (int l = 0; l < NL; ++l) {
        const float* hin = (l & 1) ? hsB : hsA;
        float* hout = (l & 1) ? hsA : hsB;
        k_layer<<<NB_W, 512, 0, stream>>>(hin, col, row_start, deg_in, ndst, f0,
                                          w1p + l * HID * HID, w2p + l * HID * HID,
                                          bvec + l * HID, nsrc, hbuf, hout, (l == NL - 1) ? 1 : 0);
    }
    k_out<<<NB_O, 256, 0, stream>>>(hbuf, Wout, bout, out);
}

// Round 8
// 1238.748 us; speedup vs baseline: 4.8018x; 1.1029x over previous
//
#include <hip/hip_runtime.h>
#include <math.h>

#define NN 50000
#define NE 800000
#define INF 512
#define HID 64
#define OUTF 40
#define NL 16
#define PADN 65
#define PACCS 17

// bf16 helpers: RNE pack, cheap unpack
__device__ __forceinline__ unsigned int f2bf(float f) {
    unsigned int u = __float_as_uint(f);
    return (u + 0x7fffu + ((u >> 16) & 1u)) >> 16;
}
__device__ __forceinline__ float bflo(unsigned int w) { return __uint_as_float(w << 16); }
__device__ __forceinline__ float bfhi(unsigned int w) { return __uint_as_float(w & 0xffff0000u); }

// ---------------- setup kernels ----------------

__global__ __launch_bounds__(256) void k_deg(const int* __restrict__ src, const int* __restrict__ dst,
                                             int* __restrict__ dout, int* __restrict__ din) {
    int e = blockIdx.x * 256 + threadIdx.x;
    if (e < NE) {
        atomicAdd(&dout[src[e]], 1);
        atomicAdd(&din[dst[e]], 1);
    }
}

__global__ __launch_bounds__(256) void k_norm(const int* __restrict__ dout, const int* __restrict__ din,
                                              float* __restrict__ ns, float* __restrict__ nd) {
    int i = blockIdx.x * 256 + threadIdx.x;
    if (i < NN) {
        ns[i] = 1.0f / sqrtf((float)max(dout[i], 1));
        nd[i] = 1.0f / sqrtf((float)max(din[i], 1));
    }
}

__global__ __launch_bounds__(256) void k_scanA(const int* __restrict__ din, int* __restrict__ incl,
                                               int* __restrict__ bsum) {
    __shared__ int lds[256];
    int i = blockIdx.x * 256 + threadIdx.x;
    int v = (i < NN) ? din[i] : 0;
    lds[threadIdx.x] = v;
    __syncthreads();
    for (int off = 1; off < 256; off <<= 1) {
        int t = (threadIdx.x >= off) ? lds[threadIdx.x - off] : 0;
        __syncthreads();
        lds[threadIdx.x] += t;
        __syncthreads();
    }
    if (i < NN) incl[i] = lds[threadIdx.x];
    if (threadIdx.x == 255) bsum[blockIdx.x] = lds[255];
}

__global__ __launch_bounds__(256) void k_scanB(int* __restrict__ bsum, int nb) {
    __shared__ int lds[256];
    int v = (threadIdx.x < nb) ? bsum[threadIdx.x] : 0;
    lds[threadIdx.x] = v;
    __syncthreads();
    for (int off = 1; off < 256; off <<= 1) {
        int t = (threadIdx.x >= off) ? lds[threadIdx.x - off] : 0;
        __syncthreads();
        lds[threadIdx.x] += t;
        __syncthreads();
    }
    if (threadIdx.x < nb) bsum[threadIdx.x] = lds[threadIdx.x] - v;  // exclusive
}

__global__ __launch_bounds__(256) void k_scanC(const int* __restrict__ incl, const int* __restrict__ din,
                                               const int* __restrict__ bsum, int* __restrict__ row_start,
                                               int* __restrict__ cursor) {
    int i = blockIdx.x * 256 + threadIdx.x;
    if (i < NN) {
        int rs = incl[i] - din[i] + bsum[i >> 8];
        row_start[i] = rs;
        cursor[i] = rs;
    }
}

__global__ __launch_bounds__(256) void k_fill(const int* __restrict__ src, const int* __restrict__ dst,
                                              int* __restrict__ cursor, int* __restrict__ col) {
    int e = blockIdx.x * 256 + threadIdx.x;
    if (e < NE) {
        int d = dst[e];
        int p = atomicAdd(&cursor[d], 1);
        col[p] = src[e];
    }
}

__global__ __launch_bounds__(256) void k_wprep(const float* __restrict__ W1, const float* __restrict__ W2,
                                               float* __restrict__ w1p, float* __restrict__ w2p) {
    int i = blockIdx.x * 256 + threadIdx.x;
    if (i < NL * HID * HID) {
        int l = i >> 12;
        int rc = i & 4095;
        int r = rc >> 6;
        int c = rc & 63;
        float beta = logf(0.5f / (float)(l + 1) + 1.0f);
        float d = (r == c) ? (1.0f - beta) : 0.0f;
        w1p[i] = beta * W1[i] + d;
        w2p[i] = beta * W2[i] + d;
    }
}

// ---------------- h0 GEMM: LDS-staged feat tile (coalesced), lane=node, wave=16-col, scalar weights ----------------
__global__ __launch_bounds__(256) void k_gemm0(const float* __restrict__ feat, const float* __restrict__ Win,
                                               const float* __restrict__ bin, const float* __restrict__ ns,
                                               unsigned int* __restrict__ hs, float* __restrict__ f0) {
    __shared__ float fS[64 * PADN];  // 64-K slice, transposed [k][node]
    int tid = threadIdx.x;
    int lane = tid & 63;
    int wv = tid >> 6;
    int nb = blockIdx.x * 64;
    int cg = __builtin_amdgcn_readfirstlane(wv) * 16;
    float acc[16];
#pragma unroll
    for (int c = 0; c < 16; c++) acc[c] = 0.0f;

    for (int kc = 0; kc < INF; kc += 64) {
        if (kc) __syncthreads();
        // stage: 64 nodes x 64 k, coalesced 256B-per-row reads, transposed LDS writes
        for (int i = tid; i < 64 * 16; i += 256) {
            int nl = i >> 4;
            int k4 = i & 15;
            int n = min(nb + nl, NN - 1);
            float4 v = *(const float4*)(feat + (size_t)n * INF + kc + k4 * 4);
            fS[(k4 * 4 + 0) * PADN + nl] = v.x;
            fS[(k4 * 4 + 1) * PADN + nl] = v.y;
            fS[(k4 * 4 + 2) * PADN + nl] = v.z;
            fS[(k4 * 4 + 3) * PADN + nl] = v.w;
        }
        __syncthreads();
        const float* wb = Win + (size_t)kc * HID + cg;
        for (int k = 0; k < 64; ++k) {
            float fk = fS[k * PADN + lane];
            const float* wr = wb + (size_t)k * HID;
#pragma unroll
            for (int c = 0; c < 16; c++) acc[c] += fk * wr[c];
        }
    }
    int node = nb + lane;
    if (node < NN) {
        float nsv = ns[node];
        const float* bp = bin + cg;
        float4* f0p = (float4*)(f0 + (size_t)node * HID + cg);
        uint2* hsp = (uint2*)(hs + ((size_t)node * HID + cg) / 2);
#pragma unroll
        for (int c4 = 0; c4 < 4; c4++) {
            float q0 = fmaxf(acc[c4 * 4 + 0] + bp[c4 * 4 + 0], 0.0f);
            float q1 = fmaxf(acc[c4 * 4 + 1] + bp[c4 * 4 + 1], 0.0f);
            float q2 = fmaxf(acc[c4 * 4 + 2] + bp[c4 * 4 + 2], 0.0f);
            float q3 = fmaxf(acc[c4 * 4 + 3] + bp[c4 * 4 + 3], 0.0f);
            float s0 = q0 * nsv, s1 = q1 * nsv, s2 = q2 * nsv, s3 = q3 * nsv;
            uint2 pk;
            pk.x = f2bf(s0) | (f2bf(s1) << 16);
            pk.y = f2bf(s2) | (f2bf(s3) << 16);
            hsp[c4] = pk;
            float4 vf = {q0 * 0.1f, q1 * 0.1f, q2 * 0.1f, q3 * 0.1f};
            f0p[c4] = vf;
        }
    }
}

// ---------------- fused layer: bf16 gathers (2 lines/row) + fp32 LDS matmul, scalar weights ----------------
__global__ __launch_bounds__(512) void k_layer(const unsigned int* __restrict__ hs_in, const int* __restrict__ col,
                                               const int* __restrict__ row_start, const int* __restrict__ din,
                                               const float* __restrict__ nd, const float* __restrict__ f0,
                                               const float* __restrict__ w1p, const float* __restrict__ w2p,
                                               const float* __restrict__ bias, const float* __restrict__ ns,
                                               float* __restrict__ h, unsigned int* __restrict__ hs_out, int write_h) {
    __shared__ float fT[HID * PADN];
    __shared__ float f0T[HID * PADN];
    __shared__ float pacc[4 * 64 * PACCS];
    int tid = threadIdx.x;
    int lane = tid & 63;
    int wv = tid >> 6;  // 0..7
    int nb = blockIdx.x * 64;
    int grp = lane >> 4;            // edge slot within a 4-edge round
    int q = lane & 15;              // dim group: 4 dims per lane (8B bf16)
    int c4o = q << 2;

    // stage f0 rows -> LDS transposed (coalesced 16B global reads)
    for (int i = tid; i < 64 * 16; i += 512) {
        int nl = i >> 4;
        int c4 = i & 15;
        int n = min(nb + nl, NN - 1);
        float4 v = *(const float4*)(f0 + (size_t)n * HID + c4 * 4);
        f0T[(c4 * 4 + 0) * PADN + nl] = v.x;
        f0T[(c4 * 4 + 1) * PADN + nl] = v.y;
        f0T[(c4 * 4 + 2) * PADN + nl] = v.z;
        f0T[(c4 * 4 + 3) * PADN + nl] = v.w;
    }

    // aggregation: wave handles 8 nodes serially; 4 bf16 row-gathers (uint2) in flight per round
    int n0 = min(nb + wv * 8, NN - 1);
    int base_cur = row_start[n0];
    int deg_cur = din[n0];
    int idx_cur = (lane < min(deg_cur, 64)) ? col[base_cur + lane] : 0;

    for (int i = 0; i < 8; ++i) {
        int nl = wv * 8 + i;
        int n = min(nb + nl, NN - 1);
        int base_nx = 0, deg_nx = 0, idx_nx = 0;
        if (i < 7) {
            int n2 = min(nb + nl + 1, NN - 1);
            base_nx = row_start[n2];
            deg_nx = din[n2];
            idx_nx = (lane < min(deg_nx, 64)) ? col[base_nx + lane] : 0;
        }
        float ax = 0.0f, ay = 0.0f, az = 0.0f, aw = 0.0f;
        int deg = deg_cur, base = base_cur, idxv = idx_cur;
        for (int done = 0; done < deg;) {
            int cnt = min(64, deg - done);
            if (done) idxv = (lane < cnt) ? col[base + done + lane] : 0;
            int e = 0;
            for (; e + 16 <= cnt; e += 16) {
                int s0 = __shfl(idxv, e + grp, 64);
                int s1 = __shfl(idxv, e + 4 + grp, 64);
                int s2 = __shfl(idxv, e + 8 + grp, 64);
                int s3 = __shfl(idxv, e + 12 + grp, 64);
                uint2 v0 = *(const uint2*)(hs_in + (size_t)s0 * 32 + q * 2);
                uint2 v1 = *(const uint2*)(hs_in + (size_t)s1 * 32 + q * 2);
                uint2 v2 = *(const uint2*)(hs_in + (size_t)s2 * 32 + q * 2);
                uint2 v3 = *(const uint2*)(hs_in + (size_t)s3 * 32 + q * 2);
                ax += (bflo(v0.x) + bflo(v1.x)) + (bflo(v2.x) + bflo(v3.x));
                ay += (bfhi(v0.x) + bfhi(v1.x)) + (bfhi(v2.x) + bfhi(v3.x));
                az += (bflo(v0.y) + bflo(v1.y)) + (bflo(v2.y) + bflo(v3.y));
                aw += (bfhi(v0.y) + bfhi(v1.y)) + (bfhi(v2.y) + bfhi(v3.y));
            }
            if (e + 8 <= cnt) {
                int s0 = __shfl(idxv, e + grp, 64);
                int s1 = __shfl(idxv, e + 4 + grp, 64);
                uint2 v0 = *(const uint2*)(hs_in + (size_t)s0 * 32 + q * 2);
                uint2 v1 = *(const uint2*)(hs_in + (size_t)s1 * 32 + q * 2);
                ax += bflo(v0.x) + bflo(v1.x);
                ay += bfhi(v0.x) + bfhi(v1.x);
                az += bflo(v0.y) + bflo(v1.y);
                aw += bfhi(v0.y) + bfhi(v1.y);
                e += 8;
            }
            if (e < cnt) {
                int ei0 = e + grp;
                int ei1 = e + 4 + grp;
                int s0 = __shfl(idxv, ei0 & 63, 64);
                int s1 = __shfl(idxv, ei1 & 63, 64);
                if (ei0 < cnt) {
                    uint2 v0 = *(const uint2*)(hs_in + (size_t)s0 * 32 + q * 2);
                    ax += bflo(v0.x); ay += bfhi(v0.x); az += bflo(v0.y); aw += bfhi(v0.y);
                }
                if (ei1 < cnt) {
                    uint2 v1 = *(const uint2*)(hs_in + (size_t)s1 * 32 + q * 2);
                    ax += bflo(v1.x); ay += bfhi(v1.x); az += bflo(v1.y); aw += bfhi(v1.y);
                }
            }
            done += cnt;
        }
        ax += __shfl_xor(ax, 16, 64); ax += __shfl_xor(ax, 32, 64);
        ay += __shfl_xor(ay, 16, 64); ay += __shfl_xor(ay, 32, 64);
        az += __shfl_xor(az, 16, 64); az += __shfl_xor(az, 32, 64);
        aw += __shfl_xor(aw, 16, 64); aw += __shfl_xor(aw, 32, 64);
        float sc = 0.9f * nd[n];
        if (grp == 0) {
            fT[(c4o + 0) * PADN + nl] = ax * sc;
            fT[(c4o + 1) * PADN + nl] = ay * sc;
            fT[(c4o + 2) * PADN + nl] = az * sc;
            fT[(c4o + 3) * PADN + nl] = aw * sc;
        }
        base_cur = base_nx; deg_cur = deg_nx; idx_cur = idx_nx;
    }
    __syncthreads();

    // matmul: lane = node. waves 0-3: f @ w1p; waves 4-7: f0 @ w2p (cg = (wv&3)*16); scalar weights
    int cgl = wv & 3;
    int cg = __builtin_amdgcn_readfirstlane(cgl) * 16;
    float acc[16];
#pragma unroll
    for (int c = 0; c < 16; c++) acc[c] = 0.0f;
    if (wv >= 4) {
        const float* w2b = w2p + cg;
        for (int k = 0; k < HID; ++k) {
            float f0k = f0T[k * PADN + lane];
            const float* w2r = w2b + (size_t)k * HID;
#pragma unroll
            for (int c = 0; c < 16; c++) acc[c] += f0k * w2r[c];
        }
        float* pp = pacc + ((size_t)cgl * 64 + lane) * PACCS;
#pragma unroll
        for (int c = 0; c < 16; c++) pp[c] = acc[c];
    } else {
        const float* w1b = w1p + cg;
        for (int k = 0; k < HID; ++k) {
            float fk = fT[k * PADN + lane];
            const float* w1r = w1b + (size_t)k * HID;
#pragma unroll
            for (int c = 0; c < 16; c++) acc[c] += fk * w1r[c];
        }
    }
    __syncthreads();
    if (wv < 4) {
        const float* pp = pacc + ((size_t)cgl * 64 + lane) * PACCS;
        int node = nb + lane;
        if (node < NN) {
            float nsv = ns[node];
            const float* bp = bias + cg;
            uint2* hsp = (uint2*)(hs_out + ((size_t)node * HID + cg) / 2);
#pragma unroll
            for (int c4 = 0; c4 < 4; c4++) {
                float q0 = fmaxf(acc[c4 * 4 + 0] + pp[c4 * 4 + 0] + bp[c4 * 4 + 0], 0.0f);
                float q1 = fmaxf(acc[c4 * 4 + 1] + pp[c4 * 4 + 1] + bp[c4 * 4 + 1], 0.0f);
                float q2 = fmaxf(acc[c4 * 4 + 2] + pp[c4 * 4 + 2] + bp[c4 * 4 + 2], 0.0f);
                float q3 = fmaxf(acc[c4 * 4 + 3] + pp[c4 * 4 + 3] + bp[c4 * 4 + 3], 0.0f);
                float s0 = q0 * nsv, s1 = q1 * nsv, s2 = q2 * nsv, s3 = q3 * nsv;
                uint2 pk;
                pk.x = f2bf(s0) | (f2bf(s1) << 16);
                pk.y = f2bf(s2) | (f2bf(s3) << 16);
                hsp[c4] = pk;
                if (write_h) {
                    float4 v = {q0, q1, q2, q3};
                    ((float4*)(h + (size_t)node * HID + cg))[c4] = v;
                }
            }
        }
    }
}

// ---------------- output: block = 128 nodes; wave pair splits the 40 cols; LDS lse reduce ----------------
__global__ __launch_bounds__(256) void k_out(const float* __restrict__ h, const float* __restrict__ Wout,
                                             const float* __restrict__ bout, float* __restrict__ out) {
    __shared__ float red_mx[4][64];
    __shared__ float red_s[4][64];
    int tid = threadIdx.x;
    int lane = tid & 63;
    int wv = tid >> 6;
    int half = wv & 1;
    int grp = wv >> 1;
    int node = blockIdx.x * 128 + grp * 64 + lane;
    int nodec = min(node, NN - 1);
    float acc[20];
#pragma unroll
    for (int c = 0; c < 20; c++) acc[c] = 0.0f;
    const float4* hr = (const float4*)(h + (size_t)nodec * HID);
    const float* wb = Wout + half * 20;
    for (int kk = 0; kk < HID / 4; ++kk) {
        float4 a = hr[kk];
        float av[4] = {a.x, a.y, a.z, a.w};
#pragma unroll
        for (int j = 0; j < 4; j++) {
            const float* wr = wb + (size_t)(kk * 4 + j) * OUTF;
#pragma unroll
            for (int c = 0; c < 20; c++) acc[c] += av[j] * wr[c];
        }
    }
    const float* bp = bout + half * 20;
#pragma unroll
    for (int c = 0; c < 20; c++) acc[c] += bp[c];
    float mx = acc[0];
#pragma unroll
    for (int c = 1; c < 20; c++) mx = fmaxf(mx, acc[c]);
    red_mx[wv][lane] = mx;
    __syncthreads();
    float gmx = fmaxf(mx, red_mx[wv ^ 1][lane]);
    float s = 0.0f;
#pragma unroll
    for (int c = 0; c < 20; c++) s += expf(acc[c] - gmx);
    red_s[wv][lane] = s;
    __syncthreads();
    float lse = logf(s + red_s[wv ^ 1][lane]) + gmx;
    if (node < NN) {
        float4* op = (float4*)(out + (size_t)node * OUTF + half * 20);
#pragma unroll
        for (int q = 0; q < 5; q++) {
            float4 v;
            v.x = acc[q * 4 + 0] - lse;
            v.y = acc[q * 4 + 1] - lse;
            v.z = acc[q * 4 + 2] - lse;
            v.w = acc[q * 4 + 3] - lse;
            op[q] = v;
        }
    }
}

extern "C" void kernel_launch(void* const* d_in, const int* in_sizes, int n_in,
                              void* d_out, int out_size, void* d_ws, size_t ws_size,
                              hipStream_t stream) {
    const float* feat = (const float*)d_in[0];
    const float* Win  = (const float*)d_in[1];
    const float* bin  = (const float*)d_in[2];
    const float* W1   = (const float*)d_in[3];
    const float* W2   = (const float*)d_in[4];
    const float* bvec = (const float*)d_in[5];
    const float* Wout = (const float*)d_in[6];
    const float* bout = (const float*)d_in[7];
    const int*   src  = (const int*)d_in[8];
    const int*   dst  = (const int*)d_in[9];
    float* out = (float*)d_out;

    char* ws = (char*)d_ws;
    size_t off = 0;
    auto take = [&](size_t bytes) {
        void* p = ws + off;
        off += (bytes + 255) & ~(size_t)255;
        return p;
    };
    int* deg_out   = (int*)take(NN * 4);
    int* deg_in    = (int*)take(NN * 4);
    int* incl      = (int*)take(NN * 4);
    int* bsum      = (int*)take(256 * 4);
    int* row_start = (int*)take(NN * 4);
    int* cursor    = (int*)take(NN * 4);
    int* col       = (int*)take(NE * 4);
    float* nsrc    = (float*)take(NN * 4);
    float* ndst    = (float*)take(NN * 4);
    float* w1p     = (float*)take((size_t)NL * HID * HID * 4);
    float* w2p     = (float*)take((size_t)NL * HID * HID * 4);
    float* f0      = (float*)take((size_t)NN * HID * 4);
    float* hbuf    = (float*)take((size_t)NN * HID * 4);
    unsigned int* hsA = (unsigned int*)take((size_t)NN * HID * 2);  // bf16
    unsigned int* hsB = (unsigned int*)take((size_t)NN * HID * 2);  // bf16

    const int NB_N = (NN + 255) / 256;   // 196
    const int NB_E = (NE + 255) / 256;   // 3125
    const int NB_W = (NN + 63) / 64;     // 782
    const int NB_O = (NN + 127) / 128;   // 391

    hipMemsetAsync(deg_out, 0, NN * 4, stream);
    hipMemsetAsync(deg_in, 0, NN * 4, stream);

    k_deg<<<NB_E, 256, 0, stream>>>(src, dst, deg_out, deg_in);
    k_norm<<<NB_N, 256, 0, stream>>>(deg_out, deg_in, nsrc, ndst);
    k_scanA<<<NB_N, 256, 0, stream>>>(deg_in, incl, bsum);
    k_scanB<<<1, 256, 0, stream>>>(bsum, NB_N);
    k_scanC<<<NB_N, 256, 0, stream>>>(incl, deg_in, bsum, row_start, cursor);
    k_fill<<<NB_E, 256, 0, stream>>>(src, dst, cursor, col);
    k_wprep<<<(NL * HID * HID + 255) / 256, 256, 0, stream>>>(W1, W2, w1p, w2p);
    k_gemm0<<<NB_W, 256, 0, stream>>>(feat, Win, bin, nsrc, hsA, f0);

    // ping-pong bf16 hs buffers (gathers read arbitrary rows; in-place would race)
    for (int l = 0; l < NL; ++l) {
        const unsigned int* hin = (l & 1) ? hsB : hsA;
        unsigned int* hout = (l & 1) ? hsA : hsB;
        k_layer<<<NB_W, 512, 0, stream>>>(hin, col, row_start, deg_in, ndst, f0,
                                          w1p + l * HID * HID, w2p + l * HID * HID,
                                          bvec + l * HID, nsrc, hbuf, hout, (l == NL - 1) ? 1 : 0);
    }
    k_out<<<NB_O, 256, 0, stream>>>(hbuf, Wout, bout, out);
}

// Round 9
// 1002.338 us; speedup vs baseline: 5.9344x; 1.2359x over previous
//
#include <hip/hip_runtime.h>
#include <math.h>

#define NN 50000
#define NE 800000
#define INF 512
#define HID 64
#define OUTF 40
#define NL 16
#define PADN 65

// bf16 helpers: RNE pack, cheap unpack
__device__ __forceinline__ unsigned int f2bf(float f) {
    unsigned int u = __float_as_uint(f);
    return (u + 0x7fffu + ((u >> 16) & 1u)) >> 16;
}
__device__ __forceinline__ float bflo(unsigned int w) { return __uint_as_float(w << 16); }
__device__ __forceinline__ float bfhi(unsigned int w) { return __uint_as_float(w & 0xffff0000u); }

// ---------------- setup kernels ----------------

__global__ __launch_bounds__(256) void k_deg(const int* __restrict__ src, const int* __restrict__ dst,
                                             int* __restrict__ dout, int* __restrict__ din) {
    int e = blockIdx.x * 256 + threadIdx.x;
    if (e < NE) {
        atomicAdd(&dout[src[e]], 1);
        atomicAdd(&din[dst[e]], 1);
    }
}

__global__ __launch_bounds__(256) void k_norm(const int* __restrict__ dout, const int* __restrict__ din,
                                              float* __restrict__ ns, float* __restrict__ nd) {
    int i = blockIdx.x * 256 + threadIdx.x;
    if (i < NN) {
        ns[i] = 1.0f / sqrtf((float)max(dout[i], 1));
        nd[i] = 1.0f / sqrtf((float)max(din[i], 1));
    }
}

__global__ __launch_bounds__(256) void k_scanA(const int* __restrict__ din, int* __restrict__ incl,
                                               int* __restrict__ bsum) {
    __shared__ int lds[256];
    int i = blockIdx.x * 256 + threadIdx.x;
    int v = (i < NN) ? din[i] : 0;
    lds[threadIdx.x] = v;
    __syncthreads();
    for (int off = 1; off < 256; off <<= 1) {
        int t = (threadIdx.x >= off) ? lds[threadIdx.x - off] : 0;
        __syncthreads();
        lds[threadIdx.x] += t;
        __syncthreads();
    }
    if (i < NN) incl[i] = lds[threadIdx.x];
    if (threadIdx.x == 255) bsum[blockIdx.x] = lds[255];
}

__global__ __launch_bounds__(256) void k_scanB(int* __restrict__ bsum, int nb) {
    __shared__ int lds[256];
    int v = (threadIdx.x < nb) ? bsum[threadIdx.x] : 0;
    lds[threadIdx.x] = v;
    __syncthreads();
    for (int off = 1; off < 256; off <<= 1) {
        int t = (threadIdx.x >= off) ? lds[threadIdx.x - off] : 0;
        __syncthreads();
        lds[threadIdx.x] += t;
        __syncthreads();
    }
    if (threadIdx.x < nb) bsum[threadIdx.x] = lds[threadIdx.x] - v;  // exclusive
}

__global__ __launch_bounds__(256) void k_scanC(const int* __restrict__ incl, const int* __restrict__ din,
                                               const int* __restrict__ bsum, int* __restrict__ row_start,
                                               int* __restrict__ cursor) {
    int i = blockIdx.x * 256 + threadIdx.x;
    if (i < NN) {
        int rs = incl[i] - din[i] + bsum[i >> 8];
        row_start[i] = rs;
        cursor[i] = rs;
    }
}

__global__ __launch_bounds__(256) void k_fill(const int* __restrict__ src, const int* __restrict__ dst,
                                              int* __restrict__ cursor, int* __restrict__ col) {
    int e = blockIdx.x * 256 + threadIdx.x;
    if (e < NE) {
        int d = dst[e];
        int p = atomicAdd(&cursor[d], 1);
        col[p] = src[e];
    }
}

__global__ __launch_bounds__(256) void k_wprep(const float* __restrict__ W1, const float* __restrict__ W2,
                                               float* __restrict__ w1p, float* __restrict__ w2p) {
    int i = blockIdx.x * 256 + threadIdx.x;
    if (i < NL * HID * HID) {
        int l = i >> 12;
        int rc = i & 4095;
        int r = rc >> 6;
        int c = rc & 63;
        float beta = logf(0.5f / (float)(l + 1) + 1.0f);
        float d = (r == c) ? (1.0f - beta) : 0.0f;
        w1p[i] = beta * W1[i] + d;
        w2p[i] = beta * W2[i] + d;
    }
}

// ---------------- h0 GEMM: LDS-staged feat (4 loads in flight), lane=node, wave=16-col, scalar weights ----------------
__global__ __launch_bounds__(256) void k_gemm0(const float* __restrict__ feat, const float* __restrict__ Win,
                                               const float* __restrict__ bin, const float* __restrict__ ns,
                                               unsigned int* __restrict__ hs, unsigned int* __restrict__ f0b) {
    __shared__ float fS[64 * PADN];  // 64-K slice, transposed [k][node]
    int tid = threadIdx.x;
    int lane = tid & 63;
    int wv = tid >> 6;
    int nb = blockIdx.x * 64;
    int cg = __builtin_amdgcn_readfirstlane(wv) * 16;
    float acc[16];
#pragma unroll
    for (int c = 0; c < 16; c++) acc[c] = 0.0f;

    for (int kc = 0; kc < INF; kc += 64) {
        if (kc) __syncthreads();
        // batched staging: 4 independent float4 loads in flight, then LDS writes
        float4 t[4];
#pragma unroll
        for (int j = 0; j < 4; j++) {
            int i = tid + j * 256;
            int nl = i >> 4;
            int k4 = i & 15;
            int n = min(nb + nl, NN - 1);
            t[j] = *(const float4*)(feat + (size_t)n * INF + kc + k4 * 4);
        }
#pragma unroll
        for (int j = 0; j < 4; j++) {
            int i = tid + j * 256;
            int nl = i >> 4;
            int k4 = i & 15;
            fS[(k4 * 4 + 0) * PADN + nl] = t[j].x;
            fS[(k4 * 4 + 1) * PADN + nl] = t[j].y;
            fS[(k4 * 4 + 2) * PADN + nl] = t[j].z;
            fS[(k4 * 4 + 3) * PADN + nl] = t[j].w;
        }
        __syncthreads();
        const float* wb = Win + (size_t)kc * HID + cg;
        for (int k = 0; k < 64; ++k) {
            float fk = fS[k * PADN + lane];
            const float* wr = wb + (size_t)k * HID;
#pragma unroll
            for (int c = 0; c < 16; c++) acc[c] += fk * wr[c];
        }
    }
    int node = nb + lane;
    if (node < NN) {
        float nsv = ns[node];
        const float* bp = bin + cg;
        uint2* hsp = (uint2*)(hs + ((size_t)node * HID + cg) / 2);
        uint2* f0p = (uint2*)(f0b + ((size_t)node * HID + cg) / 2);
#pragma unroll
        for (int c4 = 0; c4 < 4; c4++) {
            float q0 = fmaxf(acc[c4 * 4 + 0] + bp[c4 * 4 + 0], 0.0f);
            float q1 = fmaxf(acc[c4 * 4 + 1] + bp[c4 * 4 + 1], 0.0f);
            float q2 = fmaxf(acc[c4 * 4 + 2] + bp[c4 * 4 + 2], 0.0f);
            float q3 = fmaxf(acc[c4 * 4 + 3] + bp[c4 * 4 + 3], 0.0f);
            uint2 pk;
            pk.x = f2bf(q0 * nsv) | (f2bf(q1 * nsv) << 16);
            pk.y = f2bf(q2 * nsv) | (f2bf(q3 * nsv) << 16);
            hsp[c4] = pk;
            uint2 pf;
            pf.x = f2bf(q0 * 0.1f) | (f2bf(q1 * 0.1f) << 16);
            pf.y = f2bf(q2 * 0.1f) | (f2bf(q3 * 0.1f) << 16);
            f0p[c4] = pf;
        }
    }
}

// ---------------- fused layer: group-per-node agg (16 gathers in flight) + 8-wave matmul ----------------
// 512 threads = 8 waves. Block owns 64 dst-nodes. LDS = fT + f0T (33.3 KB -> 4 blocks/CU).
__global__ __launch_bounds__(512) void k_layer(const unsigned int* __restrict__ hs_in, const int* __restrict__ col,
                                               const int* __restrict__ row_start, const int* __restrict__ din,
                                               const float* __restrict__ nd, const unsigned int* __restrict__ f0b,
                                               const float* __restrict__ w1p, const float* __restrict__ w2p,
                                               const float* __restrict__ bias, const float* __restrict__ ns,
                                               float* __restrict__ h, unsigned int* __restrict__ hs_out, int write_h) {
    __shared__ float fT[HID * PADN];
    __shared__ float f0T[HID * PADN];
    int tid = threadIdx.x;
    int lane = tid & 63;
    int wv = tid >> 6;   // 0..7
    int nb = blockIdx.x * 64;
    int g = lane >> 4;   // group 0..3 (one node each)
    int ql = lane & 15;  // lane within group: owns dims [4ql, 4ql+4)

    // stage f0 (bf16) -> LDS transposed fp32
    for (int i = tid; i < 64 * 16; i += 512) {
        int nl = i >> 4;
        int q = i & 15;
        int n = min(nb + nl, NN - 1);
        uint2 v = *(const uint2*)(f0b + (size_t)n * 32 + q * 2);
        f0T[(q * 4 + 0) * PADN + nl] = bflo(v.x);
        f0T[(q * 4 + 1) * PADN + nl] = bfhi(v.x);
        f0T[(q * 4 + 2) * PADN + nl] = bflo(v.y);
        f0T[(q * 4 + 3) * PADN + nl] = bfhi(v.y);
    }

    // aggregation: each 16-lane group owns one node; 16 row-gathers in flight per window
    for (int pass = 0; pass < 2; ++pass) {
        int nl = wv * 8 + pass * 4 + g;
        int n = min(nb + nl, NN - 1);
        int base = row_start[n];
        int deg = din[n];
        float ax = 0.0f, ay = 0.0f, az = 0.0f, aw = 0.0f;
        for (int done = 0; done < deg; done += 16) {
            int cnt = min(16, deg - done);  // uniform within the group
            int idxv = (ql < cnt) ? col[base + done + ql] : 0;
            uint2 pv[16];
#pragma unroll
            for (int e = 0; e < 16; ++e) {
                int s = __shfl(idxv, (g << 4) | e, 64);
                uint2 v = {0u, 0u};
                if (e < cnt) v = *(const uint2*)(hs_in + (size_t)s * 32 + ql * 2);
                pv[e] = v;
            }
#pragma unroll
            for (int e = 0; e < 16; ++e) {
                ax += bflo(pv[e].x);
                ay += bfhi(pv[e].x);
                az += bflo(pv[e].y);
                aw += bfhi(pv[e].y);
            }
        }
        float sc = 0.9f * nd[n];
        // wave writes 4 nodes x 64 dims; banks (4ql+g) mod 32 -> exactly 2-way, free
        fT[(ql * 4 + 0) * PADN + nl] = ax * sc;
        fT[(ql * 4 + 1) * PADN + nl] = ay * sc;
        fT[(ql * 4 + 2) * PADN + nl] = az * sc;
        fT[(ql * 4 + 3) * PADN + nl] = aw * sc;
    }
    __syncthreads();

    // matmul: lane = node, wave = 8-col group; weights wave-uniform -> scalar loads
    int cg = __builtin_amdgcn_readfirstlane(wv) * 8;
    const float* w1b = w1p + cg;
    const float* w2b = w2p + cg;
    float acc[8];
#pragma unroll
    for (int c = 0; c < 8; c++) acc[c] = 0.0f;
    for (int k = 0; k < HID; ++k) {
        float fk = fT[k * PADN + lane];
        float f0k = f0T[k * PADN + lane];
        const float* w1r = w1b + (size_t)k * HID;
        const float* w2r = w2b + (size_t)k * HID;
#pragma unroll
        for (int c = 0; c < 8; c++) acc[c] += fk * w1r[c] + f0k * w2r[c];
    }
    int node = nb + lane;
    if (node < NN) {
        float nsv = ns[node];
        const float* bp = bias + cg;
        float q[8];
#pragma unroll
        for (int c = 0; c < 8; c++) q[c] = fmaxf(acc[c] + bp[c], 0.0f);
        uint2* hsp = (uint2*)(hs_out + (size_t)node * 32 + cg / 2);
#pragma unroll
        for (int c4 = 0; c4 < 2; c4++) {
            uint2 pk;
            pk.x = f2bf(q[c4 * 4 + 0] * nsv) | (f2bf(q[c4 * 4 + 1] * nsv) << 16);
            pk.y = f2bf(q[c4 * 4 + 2] * nsv) | (f2bf(q[c4 * 4 + 3] * nsv) << 16);
            hsp[c4] = pk;
        }
        if (write_h) {
            float4* hp = (float4*)(h + (size_t)node * HID + cg);
            float4 v0 = {q[0], q[1], q[2], q[3]};
            float4 v1 = {q[4], q[5], q[6], q[7]};
            hp[0] = v0;
            hp[1] = v1;
        }
    }
}

// ---------------- output: block = 128 nodes; wave pair splits the 40 cols; LDS lse reduce ----------------
__global__ __launch_bounds__(256) void k_out(const float* __restrict__ h, const float* __restrict__ Wout,
                                             const float* __restrict__ bout, float* __restrict__ out) {
    __shared__ float red_mx[4][64];
    __shared__ float red_s[4][64];
    int tid = threadIdx.x;
    int lane = tid & 63;
    int wv = tid >> 6;
    int half = wv & 1;
    int grp = wv >> 1;
    int node = blockIdx.x * 128 + grp * 64 + lane;
    int nodec = min(node, NN - 1);
    float acc[20];
#pragma unroll
    for (int c = 0; c < 20; c++) acc[c] = 0.0f;
    const float4* hr = (const float4*)(h + (size_t)nodec * HID);
    const float* wb = Wout + half * 20;
    for (int kk = 0; kk < HID / 4; ++kk) {
        float4 a = hr[kk];
        float av[4] = {a.x, a.y, a.z, a.w};
#pragma unroll
        for (int j = 0; j < 4; j++) {
            const float* wr = wb + (size_t)(kk * 4 + j) * OUTF;
#pragma unroll
            for (int c = 0; c < 20; c++) acc[c] += av[j] * wr[c];
        }
    }
    const float* bp = bout + half * 20;
#pragma unroll
    for (int c = 0; c < 20; c++) acc[c] += bp[c];
    float mx = acc[0];
#pragma unroll
    for (int c = 1; c < 20; c++) mx = fmaxf(mx, acc[c]);
    red_mx[wv][lane] = mx;
    __syncthreads();
    float gmx = fmaxf(mx, red_mx[wv ^ 1][lane]);
    float s = 0.0f;
#pragma unroll
    for (int c = 0; c < 20; c++) s += expf(acc[c] - gmx);
    red_s[wv][lane] = s;
    __syncthreads();
    float lse = logf(s + red_s[wv ^ 1][lane]) + gmx;
    if (node < NN) {
        float4* op = (float4*)(out + (size_t)node * OUTF + half * 20);
#pragma unroll
        for (int q = 0; q < 5; q++) {
            float4 v;
            v.x = acc[q * 4 + 0] - lse;
            v.y = acc[q * 4 + 1] - lse;
            v.z = acc[q * 4 + 2] - lse;
            v.w = acc[q * 4 + 3] - lse;
            op[q] = v;
        }
    }
}

extern "C" void kernel_launch(void* const* d_in, const int* in_sizes, int n_in,
                              void* d_out, int out_size, void* d_ws, size_t ws_size,
                              hipStream_t stream) {
    const float* feat = (const float*)d_in[0];
    const float* Win  = (const float*)d_in[1];
    const float* bin  = (const float*)d_in[2];
    const float* W1   = (const float*)d_in[3];
    const float* W2   = (const float*)d_in[4];
    const float* bvec = (const float*)d_in[5];
    const float* Wout = (const float*)d_in[6];
    const float* bout = (const float*)d_in[7];
    const int*   src  = (const int*)d_in[8];
    const int*   dst  = (const int*)d_in[9];
    float* out = (float*)d_out;

    char* ws = (char*)d_ws;
    size_t off = 0;
    auto take = [&](size_t bytes) {
        void* p = ws + off;
        off += (bytes + 255) & ~(size_t)255;
        return p;
    };
    int* deg_out   = (int*)take(NN * 4);
    int* deg_in    = (int*)take(NN * 4);
    int* incl      = (int*)take(NN * 4);
    int* bsum      = (int*)take(256 * 4);
    int* row_start = (int*)take(NN * 4);
    int* cursor    = (int*)take(NN * 4);
    int* col       = (int*)take(NE * 4);
    float* nsrc    = (float*)take(NN * 4);
    float* ndst    = (float*)take(NN * 4);
    float* w1p     = (float*)take((size_t)NL * HID * HID * 4);
    float* w2p     = (float*)take((size_t)NL * HID * HID * 4);
    unsigned int* f0b = (unsigned int*)take((size_t)NN * HID * 2);  // bf16
    float* hbuf    = (float*)take((size_t)NN * HID * 4);
    unsigned int* hsA = (unsigned int*)take((size_t)NN * HID * 2);  // bf16
    unsigned int* hsB = (unsigned int*)take((size_t)NN * HID * 2);  // bf16

    const int NB_N = (NN + 255) / 256;   // 196
    const int NB_E = (NE + 255) / 256;   // 3125
    const int NB_W = (NN + 63) / 64;     // 782
    const int NB_O = (NN + 127) / 128;   // 391

    hipMemsetAsync(deg_out, 0, NN * 4, stream);
    hipMemsetAsync(deg_in, 0, NN * 4, stream);

    k_deg<<<NB_E, 256, 0, stream>>>(src, dst, deg_out, deg_in);
    k_norm<<<NB_N, 256, 0, stream>>>(deg_out, deg_in, nsrc, ndst);
    k_scanA<<<NB_N, 256, 0, stream>>>(deg_in, incl, bsum);
    k_scanB<<<1, 256, 0, stream>>>(bsum, NB_N);
    k_scanC<<<NB_N, 256, 0, stream>>>(incl, deg_in, bsum, row_start, cursor);
    k_fill<<<NB_E, 256, 0, stream>>>(src, dst, cursor, col);
    k_wprep<<<(NL * HID * HID + 255) / 256, 256, 0, stream>>>(W1, W2, w1p, w2p);
    k_gemm0<<<NB_W, 256, 0, stream>>>(feat, Win, bin, nsrc, hsA, f0b);

    // ping-pong bf16 hs buffers (gathers read arbitrary rows; in-place would race)
    for (int l = 0; l < NL; ++l) {
        const unsigned int* hin = (l & 1) ? hsB : hsA;
        unsigned int* hout = (l & 1) ? hsA : hsB;
        k_layer<<<NB_W, 512, 0, stream>>>(hin, col, row_start, deg_in, ndst, f0b,
                                          w1p + l * HID * HID, w2p + l * HID * HID,
                                          bvec + l * HID, nsrc, hbuf, hout, (l == NL - 1) ? 1 : 0);
    }
    k_out<<<NB_O, 256, 0, stream>>>(hbuf, Wout, bout, out);
}